// Round 8
// baseline (6152.957 us; speedup 1.0000x reference)
//
#include <hip/hip_runtime.h>
#include <hip/hip_bf16.h>
#include <math.h>

#define NB  1024
#define NN  1000
#define NE  128
#define NH  8
#define NDK 16
#define NSC 256

typedef __attribute__((ext_vector_type(4))) float f32x4;

__device__ __forceinline__ f32x4 ld4(const float* p) {
    return *reinterpret_cast<const f32x4*>(p);
}

// ---------------- kernel 0: query[b][e] = ctx + stepc @ Wstep^T ; zero cnt[b] ----------------
__global__ __launch_bounds__(128)
void query_kernel(const float* __restrict__ ctx, const float* __restrict__ stepc,
                  const float* __restrict__ Wstep, float* __restrict__ q_ws,
                  int* __restrict__ cnt)
{
    const int b = blockIdx.x, t = threadIdx.x;
    __shared__ float sc[NSC];
    sc[t] = stepc[b * NSC + t];
    sc[t + 128] = stepc[b * NSC + t + 128];
    if (t == 0) cnt[b] = 0;            // per-launch reset (kernel-boundary visibility)
    __syncthreads();
    float acc = ctx[b * NE + t];
    const float4* w4 = reinterpret_cast<const float4*>(Wstep + (size_t)t * NSC);
    #pragma unroll 8
    for (int c4 = 0; c4 < NSC / 4; ++c4) {
        float4 w = w4[c4];
        acc += sc[4*c4] * w.x + sc[4*c4+1] * w.y + sc[4*c4+2] * w.z + sc[4*c4+3] * w.w;
    }
    q_ws[b * NE + t] = acc;
}

// ---------------- mega kernel: attn per (b,h); 8th arriver does logits for b ----------------
// attn: K+V loads fused in one mask-predicated burst (proven R7 structure).
// tail: gout matvec + lK dot + log-softmax (proven R7 logits structure).
__global__ __launch_bounds__(512, 6)
void mega_kernel(const float* __restrict__ q_ws,
                 const float* __restrict__ gK, const float* __restrict__ gV,
                 const float* __restrict__ lK, const float* __restrict__ Wout,
                 const unsigned char* __restrict__ mask,
                 float* __restrict__ heads_ws, int* __restrict__ cnt,
                 __hip_bfloat16* __restrict__ out)
{
    const int bid = blockIdx.x;           // 0..8191
    const int h = bid & (NH - 1);         // h in LOW bits: the 8 blocks of one b dispatch together
    const int b = bid >> 3;
    const int t = threadIdx.x;
    const int w = t >> 6, lane = t & 63;
    const int qq  = lane & 3;             // dk-quarter 0..3
    const int rsl = lane >> 2;            // row slot 0..15

    __shared__ float wmax[8], wsum[8];
    __shared__ __align__(16) float wred[8][16];
    __shared__ int winner;
    // logits-phase LDS (only used by winner block)
    __shared__ __align__(16) float g[NE];
    __shared__ __align__(16) float gout[NE];
    __shared__ float red[8];
    __shared__ float Mv, LSv;

    // mask dtype detect (wave-uniform): first 64 words all <=1 -> int32 mask
    const unsigned int* mw = reinterpret_cast<const unsigned int*>(mask);
    const bool m_i32 = (__ballot(mw[lane] <= 1u) == ~0ull);
    const int* mask_i = reinterpret_cast<const int*>(mask);

    // my q-quarter (16B per lane; whole wave hits one 64B line)
    const f32x4 qv = ld4(q_ws + (size_t)b * NE + h * NDK + qq * 4);

    // ---- row-mask bits (8 row-groups/wave; packed into one register) ----
    unsigned mbits = 0;
    #pragma unroll
    for (int i = 0; i < 8; ++i) {
        const int n = w * 16 + i * 128 + rsl;
        const bool dead = (n >= NN);
        const int nn = dead ? 0 : n;
        int mk = m_i32 ? (mask_i[(size_t)b * NN + nn] != 0)
                       : (mask[(size_t)b * NN + nn] != 0);
        mbits |= (unsigned)(mk | (dead ? 1 : 0)) << i;
    }

    // ---- fused K+V load burst (16 loads in flight), dot as K arrives ----
    const float* Kb = gK + (size_t)(h * NB + b) * NN * NDK;
    const float* Vb = gV + (size_t)(h * NB + b) * NN * NDK;
    f32x4 vreg[8];
    float sc[8];
    #pragma unroll
    for (int i = 0; i < 8; ++i) {
        const int n = w * 16 + i * 128 + rsl;
        const int nn = ((mbits >> i) & 1u) ? 0 : n;   // masked -> hot dummy row 0
        const size_t off = (size_t)nn * NDK + qq * 4;
        f32x4 kv = ld4(Kb + off);
        vreg[i] = ld4(Vb + off);
        sc[i] = kv.x*qv.x + kv.y*qv.y + kv.z*qv.z + kv.w*qv.w;
    }
    #pragma unroll
    for (int i = 0; i < 8; ++i) {
        float p = sc[i];
        p += __shfl_xor(p, 1);
        p += __shfl_xor(p, 2);              // all 4 quad lanes hold full dot
        sc[i] = ((mbits >> i) & 1u) ? -INFINITY : p * 0.25f;   // 1/sqrt(16)
    }

    // ---- block max ----
    float m = sc[0];
    #pragma unroll
    for (int i = 1; i < 8; ++i) m = fmaxf(m, sc[i]);
    #pragma unroll
    for (int off = 32; off > 0; off >>= 1) m = fmaxf(m, __shfl_xor(m, off));
    if (lane == 0) wmax[w] = m;
    __syncthreads();
    float M = wmax[0];
    #pragma unroll
    for (int i = 1; i < 8; ++i) M = fmaxf(M, wmax[i]);

    // ---- exp + PV FMA (V already in registers) + wave sum ----
    f32x4 acc = {0.f, 0.f, 0.f, 0.f};
    float ls = 0.f;
    #pragma unroll
    for (int i = 0; i < 8; ++i) {
        const float e = expf(sc[i] - M);    // exp(-inf)=0 for masked
        ls += e;
        acc.x += e * vreg[i].x; acc.y += e * vreg[i].y;
        acc.z += e * vreg[i].z; acc.w += e * vreg[i].w;
    }
    #pragma unroll
    for (int off = 32; off > 0; off >>= 1) ls += __shfl_xor(ls, off);
    if (lane == 0) wsum[w] = ls;            // = 4 * true wave sum (4-lane row duplication)

    // reduce acc across the 16 row-slots (stride-4 lane groups)
    #pragma unroll
    for (int off = 4; off < 64; off <<= 1) {
        acc.x += __shfl_xor(acc.x, off);
        acc.y += __shfl_xor(acc.y, off);
        acc.z += __shfl_xor(acc.z, off);
        acc.w += __shfl_xor(acc.w, off);
    }
    if (lane < 4) *reinterpret_cast<f32x4*>(&wred[w][lane * 4]) = acc;  // lane==qq here
    __syncthreads();

    if (t < NDK) {
        float S = wsum[0];
        #pragma unroll
        for (int i = 1; i < 8; ++i) S += wsum[i];
        S *= 0.25f;
        float r = wred[0][t];
        #pragma unroll
        for (int i = 1; i < 8; ++i) r += wred[i][t];
        heads_ws[(size_t)b * NE + h * NDK + t] = r / S;   // wave 0 stores, then t0 fences
    }

    // ---- winner election: 8th arriver for this b computes the logits tail ----
    __threadfence();                                    // release heads_ws (device scope)
    if (t == 0) winner = (atomicAdd(&cnt[b], 1) == NH - 1);
    __syncthreads();
    if (!winner) return;
    __threadfence();                                    // acquire other blocks' heads

    // ================= logits tail for this b (proven R7 structure) =================
    if (t < NE) g[t] = heads_ws[(size_t)b * NE + t];
    __syncthreads();

    if (t < NE) {
        float a2 = 0.f;
        const float4* w4 = reinterpret_cast<const float4*>(Wout + (size_t)t * NE);
        const float4* g4 = reinterpret_cast<const float4*>(g);
        #pragma unroll 8
        for (int e4 = 0; e4 < NE / 4; ++e4) {
            float4 wv = w4[e4]; float4 gg = g4[e4];
            a2 += wv.x*gg.x + wv.y*gg.y + wv.z*gg.z + wv.w*gg.w;
        }
        gout[t] = a2;
    }
    __syncthreads();

    const f32x4* go4 = reinterpret_cast<const f32x4*>(gout);
    float lv[2];
    #pragma unroll
    for (int i = 0; i < 2; ++i) {
        const int n = t + 512 * i;
        const bool live = (n < NN);
        const int nidx = live ? n : 0;
        int mkd = m_i32 ? (mask_i[(size_t)b * NN + nidx] != 0)
                        : (mask[(size_t)b * NN + nidx] != 0);
        mkd |= (live ? 0 : 1);
        const int nn = mkd ? 0 : n;
        const float* lp = lK + ((size_t)b * NN + nn) * NE;
        float a3 = 0.f;
        #pragma unroll
        for (int c4 = 0; c4 < NE / 4; ++c4) {
            f32x4 x = ld4(lp + 4 * c4);
            f32x4 gv = go4[c4];                 // broadcast LDS read
            a3 += x.x*gv.x + x.y*gv.y + x.z*gv.z + x.w*gv.w;
        }
        float val = tanhf(a3 * 0.08838834764831845f) * 10.0f;  // 1/sqrt(128), clip 10
        lv[i] = mkd ? -3.0e38f : val;   // finite sentinel (NaN-free compare vs ref -inf)
    }

    float mm = fmaxf(lv[0], lv[1]);
    #pragma unroll
    for (int off = 32; off > 0; off >>= 1) mm = fmaxf(mm, __shfl_xor(mm, off));
    if (lane == 0) red[w] = mm;
    __syncthreads();
    if (t == 0) {
        float m2 = red[0];
        #pragma unroll
        for (int i = 1; i < 8; ++i) m2 = fmaxf(m2, red[i]);
        Mv = m2;
    }
    __syncthreads();
    const float M2 = Mv;
    float s2 = expf(lv[0] - M2) + expf(lv[1] - M2);   // exp(-3e38 - M) == 0
    #pragma unroll
    for (int off = 32; off > 0; off >>= 1) s2 += __shfl_xor(s2, off);
    if (lane == 0) red[w] = s2;
    __syncthreads();
    if (t == 0) {
        float ss = 0.f;
        #pragma unroll
        for (int i = 0; i < 8; ++i) ss += red[i];
        LSv = M2 + logf(ss);
    }
    __syncthreads();
    const float LS = LSv;
    #pragma unroll
    for (int i = 0; i < 2; ++i) {
        const int n = t + 512 * i;
        if (n < NN)
            out[(size_t)b * NN + n] = __float2bfloat16(lv[i] - LS);  // -3e38-LS stays -3e38
    }
}

// ---------------- fallback: proven fused single-kernel (R2) ----------------
__global__ __launch_bounds__(256, 4)
void evrp_decoder_fused(const float* __restrict__ ctx, const float* __restrict__ stepc,
                        const float* __restrict__ Wstep, const float* __restrict__ gK,
                        const float* __restrict__ gV, const float* __restrict__ lK,
                        const float* __restrict__ Wout, const unsigned char* __restrict__ mask,
                        __hip_bfloat16* __restrict__ out)
{
    const int b = blockIdx.x;
    const int t = threadIdx.x;
    __shared__ __align__(16) float q[NE];
    __shared__ __align__(16) float sc_l[NH * NN];
    __shared__ __align__(16) float g[NE];
    __shared__ __align__(16) float gout[NE];
    __shared__ __align__(16) float red[256];
    __shared__ __align__(16) float ovl[1024];
    __shared__ float mh[NH];
    __shared__ float rinv[NH];
    __shared__ float Mv, Sv;
    __shared__ int mtype;

    if (t == 0) {
        const unsigned int* mi = reinterpret_cast<const unsigned int*>(mask);
        int ok = 1;
        for (int i = 0; i < 64; ++i) ok = ok && (mi[i] <= 1u);
        mtype = ok;
    }
    red[t] = stepc[b * NSC + t];
    __syncthreads();
    const int m_i32 = mtype;
    if (t < NE) {
        float acc = ctx[b * NE + t];
        const float4* w4 = reinterpret_cast<const float4*>(Wstep + t * NSC);
        #pragma unroll 8
        for (int c4 = 0; c4 < NSC / 4; ++c4) {
            float4 w = w4[c4];
            acc += red[c4*4+0]*w.x + red[c4*4+1]*w.y + red[c4*4+2]*w.z + red[c4*4+3]*w.w;
        }
        q[t] = acc;
    }
    __syncthreads();
    const int* mask_i = reinterpret_cast<const int*>(mask);
    for (int n = t; n < NN; n += 256) {
        bool mk = m_i32 ? (mask_i[b * NN + n] != 0) : (mask[b * NN + n] != 0);
        if (mk) {
            #pragma unroll
            for (int h = 0; h < NH; ++h) sc_l[h * NN + n] = -INFINITY;
        } else {
            #pragma unroll
            for (int h = 0; h < NH; ++h) {
                const float4* k4 = reinterpret_cast<const float4*>(gK + (((size_t)h*NB + b)*NN + n)*NDK);
                const float4* q4 = reinterpret_cast<const float4*>(q + h * NDK);
                float acc = 0.f;
                #pragma unroll
                for (int i = 0; i < 4; ++i) {
                    float4 kv = k4[i]; float4 qv = q4[i];
                    acc += kv.x*qv.x + kv.y*qv.y + kv.z*qv.z + kv.w*qv.w;
                }
                sc_l[h * NN + n] = acc * 0.25f;
            }
        }
    }
    __syncthreads();
    {
        const int h = t >> 5, i = t & 31;
        float m = -INFINITY;
        for (int n = i; n < NN; n += 32) m = fmaxf(m, sc_l[h * NN + n]);
        red[t] = m;
        __syncthreads();
        if (t < NH) {
            float mm = -INFINITY;
            for (int i2 = 0; i2 < 32; ++i2) mm = fmaxf(mm, red[t * 32 + i2]);
            mh[t] = mm;
        }
        __syncthreads();
        const float mhh = mh[h];
        float s = 0.f;
        for (int n = i; n < NN; n += 32) {
            float ev = expf(sc_l[h * NN + n] - mhh);
            sc_l[h * NN + n] = ev;
            s += ev;
        }
        red[t] = s;
        __syncthreads();
        if (t < NH) {
            float ss = 0.f;
            for (int i2 = 0; i2 < 32; ++i2) ss += red[t * 32 + i2];
            rinv[t] = 1.0f / ss;
        }
        __syncthreads();
    }
    {
        float4* hp4 = reinterpret_cast<float4*>(ovl);
        const int h = t >> 5, rem = t & 31, kq = rem >> 3, j = rem & 7;
        const float* vbase = gV + (((size_t)h * NB + b) * NN) * NDK + kq * 4;
        float4 acc = {0.f, 0.f, 0.f, 0.f};
        for (int n = j; n < NN; n += 8) {
            float p = sc_l[h * NN + n];
            if (p != 0.f) {
                float4 v = *reinterpret_cast<const float4*>(vbase + (size_t)n * NDK);
                acc.x += p*v.x; acc.y += p*v.y; acc.z += p*v.z; acc.w += p*v.w;
            }
        }
        hp4[(h * 4 + kq) * 8 + j] = acc;
    }
    __syncthreads();
    if (t < NE) {
        const int h = t >> 4, k = t & 15, kq = k >> 2, kc = k & 3;
        float s = 0.f;
        #pragma unroll
        for (int j = 0; j < 8; ++j) s += ovl[((h * 4 + kq) * 8 + j) * 4 + kc];
        g[t] = s * rinv[h];
    }
    __syncthreads();
    if (t < NE) {
        float acc = 0.f;
        const float4* w4 = reinterpret_cast<const float4*>(Wout + t * NE);
        const float4* g4 = reinterpret_cast<const float4*>(g);
        #pragma unroll 8
        for (int e4 = 0; e4 < NE / 4; ++e4) {
            float4 w = w4[e4]; float4 gg = g4[e4];
            acc += w.x*gg.x + w.y*gg.y + w.z*gg.z + w.w*gg.w;
        }
        gout[t] = acc;
    }
    __syncthreads();
    float* llds = ovl;
    for (int n = t; n < NN; n += 256) {
        bool mk = m_i32 ? (mask_i[b * NN + n] != 0) : (mask[b * NN + n] != 0);
        float val;
        if (mk) val = -INFINITY;
        else {
            const float4* lk4 = reinterpret_cast<const float4*>(lK + ((size_t)b * NN + n) * NE);
            const float4* go4 = reinterpret_cast<const float4*>(gout);
            float acc = 0.f;
            #pragma unroll 8
            for (int e4 = 0; e4 < NE / 4; ++e4) {
                float4 lvv = lk4[e4]; float4 gv = go4[e4];
                acc += lvv.x*gv.x + lvv.y*gv.y + lvv.z*gv.z + lvv.w*gv.w;
            }
            val = tanhf(acc * 0.08838834764831845f) * 10.0f;
        }
        llds[n] = val;
    }
    __syncthreads();
    {
        float m = -INFINITY;
        for (int n = t; n < NN; n += 256) m = fmaxf(m, llds[n]);
        red[t] = m;
        __syncthreads();
        for (int s2 = 128; s2 > 0; s2 >>= 1) {
            if (t < s2) red[t] = fmaxf(red[t], red[t + s2]);
            __syncthreads();
        }
        if (t == 0) Mv = red[0];
        __syncthreads();
        const float M = Mv;
        float s = 0.f;
        for (int n = t; n < NN; n += 256) s += expf(llds[n] - M);
        red[t] = s;
        __syncthreads();
        for (int s2 = 128; s2 > 0; s2 >>= 1) {
            if (t < s2) red[t] += red[t + s2];
            __syncthreads();
        }
        if (t == 0) Sv = logf(red[0]);
        __syncthreads();
        const float LS = M + Sv;
        for (int n = t; n < NN; n += 256) {
            float l = llds[n];
            float r = (l == -INFINITY) ? -3.0e38f : (l - LS);
            out[(size_t)b * NN + n] = __float2bfloat16(r);
        }
    }
}

extern "C" void kernel_launch(void* const* d_in, const int* in_sizes, int n_in,
                              void* d_out, int out_size, void* d_ws, size_t ws_size,
                              hipStream_t stream) {
    const float* ctx   = (const float*)d_in[0];
    const float* stepc = (const float*)d_in[1];
    const float* Wstep = (const float*)d_in[2];
    const float* gK    = (const float*)d_in[3];
    const float* gV    = (const float*)d_in[4];
    const float* lK    = (const float*)d_in[5];
    const float* Wout  = (const float*)d_in[6];
    const unsigned char* mask = (const unsigned char*)d_in[7];
    __hip_bfloat16* out = (__hip_bfloat16*)d_out;

    const size_t need = (size_t)NB * NE * 4 * 2 + (size_t)NB * 4;  // q_ws + heads_ws + cnt
    if (ws_size >= need) {
        float* q_ws     = (float*)d_ws;
        float* heads_ws = q_ws + (size_t)NB * NE;
        int*   cnt      = (int*)(heads_ws + (size_t)NB * NE);
        query_kernel<<<dim3(NB),      dim3(128), 0, stream>>>(ctx, stepc, Wstep, q_ws, cnt);
        mega_kernel <<<dim3(NB * NH), dim3(512), 0, stream>>>(q_ws, gK, gV, lK, Wout, mask,
                                                              heads_ws, cnt, out);
    } else {
        evrp_decoder_fused<<<dim3(NB), dim3(256), 0, stream>>>(
            ctx, stepc, Wstep, gK, gV, lK, Wout, mask, out);
    }
}

// Round 9
// 219.922 us; speedup vs baseline: 27.9779x; 27.9779x over previous
//
#include <hip/hip_runtime.h>
#include <hip/hip_bf16.h>
#include <math.h>

#define NB  1024
#define NN  1000
#define NE  128
#define NH  8
#define NDK 16
#define NSC 256

typedef __attribute__((ext_vector_type(4))) float f32x4;

__device__ __forceinline__ f32x4 ld4(const float* p) {
    return *reinterpret_cast<const f32x4*>(p);
}

// ---------------- kernel 0: query[b][e] = ctx + stepc @ Wstep^T ----------------
__global__ __launch_bounds__(128)
void query_kernel(const float* __restrict__ ctx, const float* __restrict__ stepc,
                  const float* __restrict__ Wstep, float* __restrict__ q_ws)
{
    const int b = blockIdx.x, t = threadIdx.x;
    __shared__ float sc[NSC];
    sc[t] = stepc[b * NSC + t];
    sc[t + 128] = stepc[b * NSC + t + 128];
    __syncthreads();
    float acc = ctx[b * NE + t];
    const float4* w4 = reinterpret_cast<const float4*>(Wstep + (size_t)t * NSC);
    #pragma unroll 8
    for (int c4 = 0; c4 < NSC / 4; ++c4) {
        float4 w = w4[c4];
        acc += sc[4*c4] * w.x + sc[4*c4+1] * w.y + sc[4*c4+2] * w.z + sc[4*c4+3] * w.w;
    }
    q_ws[b * NE + t] = acc;
}

// ---------------- fused kernel: one block per b; attn (8 heads) + logits, all block-local ----------------
// No cross-block communication, no fences. 512 thr = 8 waves; grid 1024 = 4 blocks/CU, all resident.
// Inner attn structure proven in R7: 4 lanes/row, fused mask-predicated K+V burst, shfl reductions.
__global__ __launch_bounds__(512, 4)
void fused_kernel(const float* __restrict__ q_ws,
                  const float* __restrict__ gK, const float* __restrict__ gV,
                  const float* __restrict__ lK, const float* __restrict__ Wout,
                  const unsigned char* __restrict__ mask,
                  __hip_bfloat16* __restrict__ out)
{
    const int b = blockIdx.x;
    const int t = threadIdx.x;
    const int w = t >> 6, lane = t & 63;
    const int qq  = lane & 3;             // dk-quarter 0..3
    const int rsl = lane >> 2;            // row slot 0..15

    __shared__ float wmax[2][8], wsum[2][8];
    __shared__ __align__(16) float wred[2][8][16];
    __shared__ __align__(16) float g[NE];       // concat heads
    __shared__ __align__(16) float gout[NE];
    __shared__ float red[8];
    __shared__ float Mv, LSv;

    // mask dtype detect (wave-uniform): first 64 words all <=1 -> int32 mask
    const unsigned int* mw = reinterpret_cast<const unsigned int*>(mask);
    const bool m_i32 = (__ballot(mw[lane] <= 1u) == ~0ull);
    const int* mask_i = reinterpret_cast<const int*>(mask);

    // ---- row-mask bits: loaded ONCE, reused by all 8 heads ----
    unsigned mbits = 0;
    #pragma unroll
    for (int i = 0; i < 8; ++i) {
        const int n = w * 16 + i * 128 + rsl;
        const bool dead = (n >= NN);
        const int nn = dead ? 0 : n;
        int mk = m_i32 ? (mask_i[(size_t)b * NN + nn] != 0)
                       : (mask[(size_t)b * NN + nn] != 0);
        mbits |= (unsigned)(mk | (dead ? 1 : 0)) << i;
    }

    // ---- attention, head-sequential; parity LDS double-buffer -> 2 barriers/head ----
    #pragma unroll 1
    for (int h = 0; h < NH; ++h) {
        const int pb = h & 1;
        const f32x4 qv = ld4(q_ws + (size_t)b * NE + h * NDK + qq * 4);
        const float* Kb = gK + (size_t)(h * NB + b) * NN * NDK;
        const float* Vb = gV + (size_t)(h * NB + b) * NN * NDK;

        f32x4 vreg[8];
        float sc[8];
        #pragma unroll
        for (int i = 0; i < 8; ++i) {
            const int n = w * 16 + i * 128 + rsl;
            const int nn = ((mbits >> i) & 1u) ? 0 : n;   // masked -> hot dummy row 0
            const size_t off = (size_t)nn * NDK + qq * 4;
            f32x4 kv = ld4(Kb + off);
            vreg[i] = ld4(Vb + off);
            sc[i] = kv.x*qv.x + kv.y*qv.y + kv.z*qv.z + kv.w*qv.w;
        }
        #pragma unroll
        for (int i = 0; i < 8; ++i) {
            float p = sc[i];
            p += __shfl_xor(p, 1);
            p += __shfl_xor(p, 2);          // all 4 quad lanes hold full dot
            sc[i] = ((mbits >> i) & 1u) ? -INFINITY : p * 0.25f;   // 1/sqrt(16)
        }

        float m = sc[0];
        #pragma unroll
        for (int i = 1; i < 8; ++i) m = fmaxf(m, sc[i]);
        #pragma unroll
        for (int off = 32; off > 0; off >>= 1) m = fmaxf(m, __shfl_xor(m, off));
        if (lane == 0) wmax[pb][w] = m;
        __syncthreads();
        float M = wmax[pb][0];
        #pragma unroll
        for (int i = 1; i < 8; ++i) M = fmaxf(M, wmax[pb][i]);

        f32x4 acc = {0.f, 0.f, 0.f, 0.f};
        float ls = 0.f;
        #pragma unroll
        for (int i = 0; i < 8; ++i) {
            const float e = expf(sc[i] - M);   // exp(-inf)=0 for masked
            ls += e;
            acc.x += e * vreg[i].x; acc.y += e * vreg[i].y;
            acc.z += e * vreg[i].z; acc.w += e * vreg[i].w;
        }
        #pragma unroll
        for (int off = 32; off > 0; off >>= 1) ls += __shfl_xor(ls, off);
        if (lane == 0) wsum[pb][w] = ls;       // = 4 * true wave sum (quad duplication)

        #pragma unroll
        for (int off = 4; off < 64; off <<= 1) {
            acc.x += __shfl_xor(acc.x, off);
            acc.y += __shfl_xor(acc.y, off);
            acc.z += __shfl_xor(acc.z, off);
            acc.w += __shfl_xor(acc.w, off);
        }
        if (lane < 4) *reinterpret_cast<f32x4*>(&wred[pb][w][lane * 4]) = acc;
        __syncthreads();

        if (t < NDK) {
            float S = wsum[pb][0];
            #pragma unroll
            for (int i = 1; i < 8; ++i) S += wsum[pb][i];
            S *= 0.25f;
            float r = wred[pb][0][t];
            #pragma unroll
            for (int i = 1; i < 8; ++i) r += wred[pb][i][t];
            g[h * NDK + t] = r / S;
        }
        // safe without extra barrier: next head writes the OTHER parity buffers,
        // and this head's g-write lands before this thread's next barrier.
    }
    __syncthreads();                            // g[128] complete

    // ---------------- logits tail (proven R7 structure) ----------------
    if (t < NE) {
        float a2 = 0.f;
        const float4* w4 = reinterpret_cast<const float4*>(Wout + (size_t)t * NE);
        const float4* g4 = reinterpret_cast<const float4*>(g);
        #pragma unroll 8
        for (int e4 = 0; e4 < NE / 4; ++e4) {
            float4 wv = w4[e4]; float4 gg = g4[e4];
            a2 += wv.x*gg.x + wv.y*gg.y + wv.z*gg.z + wv.w*gg.w;
        }
        gout[t] = a2;
    }
    __syncthreads();

    const f32x4* go4 = reinterpret_cast<const f32x4*>(gout);
    float lv[2];
    #pragma unroll
    for (int i = 0; i < 2; ++i) {
        const int n = t + 512 * i;
        const bool live = (n < NN);
        const int nidx = live ? n : 0;
        int mkd = m_i32 ? (mask_i[(size_t)b * NN + nidx] != 0)
                        : (mask[(size_t)b * NN + nidx] != 0);
        mkd |= (live ? 0 : 1);
        const int nn = mkd ? 0 : n;
        const float* lp = lK + ((size_t)b * NN + nn) * NE;
        float a3 = 0.f;
        #pragma unroll
        for (int c4 = 0; c4 < NE / 4; ++c4) {
            f32x4 x = ld4(lp + 4 * c4);
            f32x4 gv = go4[c4];                 // broadcast LDS read
            a3 += x.x*gv.x + x.y*gv.y + x.z*gv.z + x.w*gv.w;
        }
        float val = tanhf(a3 * 0.08838834764831845f) * 10.0f;  // 1/sqrt(128), clip 10
        lv[i] = mkd ? -3.0e38f : val;   // finite sentinel (NaN-free compare vs ref -inf)
    }

    float mm = fmaxf(lv[0], lv[1]);
    #pragma unroll
    for (int off = 32; off > 0; off >>= 1) mm = fmaxf(mm, __shfl_xor(mm, off));
    if (lane == 0) red[w] = mm;
    __syncthreads();
    if (t == 0) {
        float m2 = red[0];
        #pragma unroll
        for (int i = 1; i < 8; ++i) m2 = fmaxf(m2, red[i]);
        Mv = m2;
    }
    __syncthreads();
    const float M2 = Mv;
    float s2 = expf(lv[0] - M2) + expf(lv[1] - M2);   // exp(-3e38 - M) == 0
    #pragma unroll
    for (int off = 32; off > 0; off >>= 1) s2 += __shfl_xor(s2, off);
    if (lane == 0) red[w] = s2;
    __syncthreads();
    if (t == 0) {
        float ss = 0.f;
        #pragma unroll
        for (int i = 0; i < 8; ++i) ss += red[i];
        LSv = M2 + logf(ss);
    }
    __syncthreads();
    const float LS = LSv;
    #pragma unroll
    for (int i = 0; i < 2; ++i) {
        const int n = t + 512 * i;
        if (n < NN)
            out[(size_t)b * NN + n] = __float2bfloat16(lv[i] - LS);  // -3e38-LS stays -3e38
    }
}

// ---------------- fallback: proven fused single-kernel (R2) ----------------
__global__ __launch_bounds__(256, 4)
void evrp_decoder_fused(const float* __restrict__ ctx, const float* __restrict__ stepc,
                        const float* __restrict__ Wstep, const float* __restrict__ gK,
                        const float* __restrict__ gV, const float* __restrict__ lK,
                        const float* __restrict__ Wout, const unsigned char* __restrict__ mask,
                        __hip_bfloat16* __restrict__ out)
{
    const int b = blockIdx.x;
    const int t = threadIdx.x;
    __shared__ __align__(16) float q[NE];
    __shared__ __align__(16) float sc_l[NH * NN];
    __shared__ __align__(16) float g[NE];
    __shared__ __align__(16) float gout[NE];
    __shared__ __align__(16) float red[256];
    __shared__ __align__(16) float ovl[1024];
    __shared__ float mh[NH];
    __shared__ float rinv[NH];
    __shared__ float Mv, Sv;
    __shared__ int mtype;

    if (t == 0) {
        const unsigned int* mi = reinterpret_cast<const unsigned int*>(mask);
        int ok = 1;
        for (int i = 0; i < 64; ++i) ok = ok && (mi[i] <= 1u);
        mtype = ok;
    }
    red[t] = stepc[b * NSC + t];
    __syncthreads();
    const int m_i32 = mtype;
    if (t < NE) {
        float acc = ctx[b * NE + t];
        const float4* w4 = reinterpret_cast<const float4*>(Wstep + t * NSC);
        #pragma unroll 8
        for (int c4 = 0; c4 < NSC / 4; ++c4) {
            float4 w = w4[c4];
            acc += red[c4*4+0]*w.x + red[c4*4+1]*w.y + red[c4*4+2]*w.z + red[c4*4+3]*w.w;
        }
        q[t] = acc;
    }
    __syncthreads();
    const int* mask_i = reinterpret_cast<const int*>(mask);
    for (int n = t; n < NN; n += 256) {
        bool mk = m_i32 ? (mask_i[b * NN + n] != 0) : (mask[b * NN + n] != 0);
        if (mk) {
            #pragma unroll
            for (int h = 0; h < NH; ++h) sc_l[h * NN + n] = -INFINITY;
        } else {
            #pragma unroll
            for (int h = 0; h < NH; ++h) {
                const float4* k4 = reinterpret_cast<const float4*>(gK + (((size_t)h*NB + b)*NN + n)*NDK);
                const float4* q4 = reinterpret_cast<const float4*>(q + h * NDK);
                float acc = 0.f;
                #pragma unroll
                for (int i = 0; i < 4; ++i) {
                    float4 kv = k4[i]; float4 qv = q4[i];
                    acc += kv.x*qv.x + kv.y*qv.y + kv.z*qv.z + kv.w*qv.w;
                }
                sc_l[h * NN + n] = acc * 0.25f;
            }
        }
    }
    __syncthreads();
    {
        const int h = t >> 5, i = t & 31;
        float m = -INFINITY;
        for (int n = i; n < NN; n += 32) m = fmaxf(m, sc_l[h * NN + n]);
        red[t] = m;
        __syncthreads();
        if (t < NH) {
            float mm = -INFINITY;
            for (int i2 = 0; i2 < 32; ++i2) mm = fmaxf(mm, red[t * 32 + i2]);
            mh[t] = mm;
        }
        __syncthreads();
        const float mhh = mh[h];
        float s = 0.f;
        for (int n = i; n < NN; n += 32) {
            float ev = expf(sc_l[h * NN + n] - mhh);
            sc_l[h * NN + n] = ev;
            s += ev;
        }
        red[t] = s;
        __syncthreads();
        if (t < NH) {
            float ss = 0.f;
            for (int i2 = 0; i2 < 32; ++i2) ss += red[t * 32 + i2];
            rinv[t] = 1.0f / ss;
        }
        __syncthreads();
    }
    {
        float4* hp4 = reinterpret_cast<float4*>(ovl);
        const int h = t >> 5, rem = t & 31, kq = rem >> 3, j = rem & 7;
        const float* vbase = gV + (((size_t)h * NB + b) * NN) * NDK + kq * 4;
        float4 acc = {0.f, 0.f, 0.f, 0.f};
        for (int n = j; n < NN; n += 8) {
            float p = sc_l[h * NN + n];
            if (p != 0.f) {
                float4 v = *reinterpret_cast<const float4*>(vbase + (size_t)n * NDK);
                acc.x += p*v.x; acc.y += p*v.y; acc.z += p*v.z; acc.w += p*v.w;
            }
        }
        hp4[(h * 4 + kq) * 8 + j] = acc;
    }
    __syncthreads();
    if (t < NE) {
        const int h = t >> 4, k = t & 15, kq = k >> 2, kc = k & 3;
        float s = 0.f;
        #pragma unroll
        for (int j = 0; j < 8; ++j) s += ovl[((h * 4 + kq) * 8 + j) * 4 + kc];
        g[t] = s * rinv[h];
    }
    __syncthreads();
    if (t < NE) {
        float acc = 0.f;
        const float4* w4 = reinterpret_cast<const float4*>(Wout + t * NE);
        const float4* g4 = reinterpret_cast<const float4*>(g);
        #pragma unroll 8
        for (int e4 = 0; e4 < NE / 4; ++e4) {
            float4 w = w4[e4]; float4 gg = g4[e4];
            acc += w.x*gg.x + w.y*gg.y + w.z*gg.z + w.w*gg.w;
        }
        gout[t] = acc;
    }
    __syncthreads();
    float* llds = ovl;
    for (int n = t; n < NN; n += 256) {
        bool mk = m_i32 ? (mask_i[b * NN + n] != 0) : (mask[b * NN + n] != 0);
        float val;
        if (mk) val = -INFINITY;
        else {
            const float4* lk4 = reinterpret_cast<const float4*>(lK + ((size_t)b * NN + n) * NE);
            const float4* go4 = reinterpret_cast<const float4*>(gout);
            float acc = 0.f;
            #pragma unroll 8
            for (int e4 = 0; e4 < NE / 4; ++e4) {
                float4 lvv = lk4[e4]; float4 gv = go4[e4];
                acc += lvv.x*gv.x + lvv.y*gv.y + lvv.z*gv.z + lvv.w*gv.w;
            }
            val = tanhf(acc * 0.08838834764831845f) * 10.0f;
        }
        llds[n] = val;
    }
    __syncthreads();
    {
        float m = -INFINITY;
        for (int n = t; n < NN; n += 256) m = fmaxf(m, llds[n]);
        red[t] = m;
        __syncthreads();
        for (int s2 = 128; s2 > 0; s2 >>= 1) {
            if (t < s2) red[t] = fmaxf(red[t], red[t + s2]);
            __syncthreads();
        }
        if (t == 0) Mv = red[0];
        __syncthreads();
        const float M = Mv;
        float s = 0.f;
        for (int n = t; n < NN; n += 256) s += expf(llds[n] - M);
        red[t] = s;
        __syncthreads();
        for (int s2 = 128; s2 > 0; s2 >>= 1) {
            if (t < s2) red[t] += red[t + s2];
            __syncthreads();
        }
        if (t == 0) Sv = logf(red[0]);
        __syncthreads();
        const float LS = M + Sv;
        for (int n = t; n < NN; n += 256) {
            float l = llds[n];
            float r = (l == -INFINITY) ? -3.0e38f : (l - LS);
            out[(size_t)b * NN + n] = __float2bfloat16(r);
        }
    }
}

extern "C" void kernel_launch(void* const* d_in, const int* in_sizes, int n_in,
                              void* d_out, int out_size, void* d_ws, size_t ws_size,
                              hipStream_t stream) {
    const float* ctx   = (const float*)d_in[0];
    const float* stepc = (const float*)d_in[1];
    const float* Wstep = (const float*)d_in[2];
    const float* gK    = (const float*)d_in[3];
    const float* gV    = (const float*)d_in[4];
    const float* lK    = (const float*)d_in[5];
    const float* Wout  = (const float*)d_in[6];
    const unsigned char* mask = (const unsigned char*)d_in[7];
    __hip_bfloat16* out = (__hip_bfloat16*)d_out;

    const size_t need = (size_t)NB * NE * 4;   // q_ws = 512 KB
    if (ws_size >= need) {
        float* q_ws = (float*)d_ws;
        query_kernel<<<dim3(NB), dim3(128), 0, stream>>>(ctx, stepc, Wstep, q_ws);
        fused_kernel<<<dim3(NB), dim3(512), 0, stream>>>(q_ws, gK, gV, lK, Wout, mask, out);
    } else {
        evrp_decoder_fused<<<dim3(NB), dim3(256), 0, stream>>>(
            ctx, stepc, Wstep, gK, gV, lK, Wout, mask, out);
    }
}